// Round 3
// baseline (160.504 us; speedup 1.0000x reference)
//
#include <hip/hip_runtime.h>
#include <math.h>

#define EPSF 1e-8f

// Sum of sqrt(clip(eigvals,1e-8)) of a symmetric 3x3.
// fp64 ONLY for the cancellation-sensitive invariants (q, b, p2, detB, r);
// transcendentals (acos/cos) and eigen sqrts in fp32 hardware ops.
// No fp64 division: r = 0.5*detB*(p2/6)^{-3/2} via rsqrt_f64.
__device__ __forceinline__ float tr_sqrt_eig(double a00, double a11, double a22,
                                             double a01, double a02, double a12)
{
    double q = (a00 + a11 + a22) * (1.0 / 3.0);
    double b00 = a00 - q, b11 = a11 - q, b22 = a22 - q;
    double p1 = a01 * a01 + a02 * a02 + a12 * a12;
    double p2 = b00 * b00 + b11 * b11 + b22 * b22 + 2.0 * p1;

    if (p2 <= 1e-30) {   // triple-degenerate: all eigs = q
        return 3.0f * sqrtf(fmaxf((float)q, EPSF));
    }

    double x = p2 * (1.0 / 6.0);
    double inv = rsqrt(x);          // (p2/6)^{-1/2}
    double p = x * inv;             // sqrt(p2/6)
    double detB = b00 * (b11 * b22 - a12 * a12)
                - a01 * (a01 * b22 - a12 * a02)
                + a02 * (a01 * a12 - b11 * a02);
    double r = 0.5 * detB * (inv * inv * inv);
    r = fmin(1.0, fmax(-1.0, r));

    float phi = acosf((float)r) * (1.0f / 3.0f);
    float qf = (float)q;
    float tp = 2.0f * (float)p;
    float e0 = qf + tp * cosf(phi);
    float e1 = qf + tp * cosf(phi - 2.0943951023931953f);  // -2*pi/3
    float e2 = qf + tp * cosf(phi + 2.0943951023931953f);  // +2*pi/3
    return sqrtf(fmaxf(e0, EPSF)) + sqrtf(fmaxf(e1, EPSF)) + sqrtf(fmaxf(e2, EPSF));
}

// 4 Gaussians per thread: all global accesses are aligned float4.
// block=64 (one wave) x 4096 blocks -> 16 light workgroups/CU, smooth tail.
__global__ __launch_bounds__(64) void wasserstein_kernel(
    const float* __restrict__ loc1, const float* __restrict__ scale1,
    const float* __restrict__ rot1, const float* __restrict__ loc2,
    const float* __restrict__ scale2, const float* __restrict__ rot2,
    float* __restrict__ out, int B4)
{
    int t = blockIdx.x * blockDim.x + threadIdx.x;
    if (t >= B4) return;

    const float4* l1p = (const float4*)loc1   + 3 * t;
    const float4* l2p = (const float4*)loc2   + 3 * t;
    const float4* s1p = (const float4*)scale1 + 3 * t;
    const float4* s2p = (const float4*)scale2 + 3 * t;
    const float4* r1p = (const float4*)rot1   + 9 * t;
    const float4* r2p = (const float4*)rot2   + 9 * t;

    // ---- Phase A: location difference ----
    float loc_diff2[4];
    {
        float L1[12], L2[12];
#pragma unroll
        for (int k = 0; k < 3; k++) {
            float4 a = l1p[k], b = l2p[k];
            L1[4 * k + 0] = a.x; L1[4 * k + 1] = a.y; L1[4 * k + 2] = a.z; L1[4 * k + 3] = a.w;
            L2[4 * k + 0] = b.x; L2[4 * k + 1] = b.y; L2[4 * k + 2] = b.z; L2[4 * k + 3] = b.w;
        }
#pragma unroll
        for (int g = 0; g < 4; g++) {
            float d0 = L1[3 * g + 0] - L2[3 * g + 0];
            float d1 = L1[3 * g + 1] - L2[3 * g + 1];
            float d2 = L1[3 * g + 2] - L2[3 * g + 2];
            loc_diff2[g] = d0 * d0 + d1 * d1 + d2 * d2;
        }
    }

    // ---- Phase B: cov2 (symmetric, 6 entries per g) + trace ----
    float cov2[4][6];   // [g][{00,11,22,01,02,12}]
    float tr_cov2[4];
    {
        float S2[12], R2[36];
#pragma unroll
        for (int k = 0; k < 3; k++) {
            float4 v = s2p[k];
            S2[4 * k + 0] = v.x; S2[4 * k + 1] = v.y; S2[4 * k + 2] = v.z; S2[4 * k + 3] = v.w;
        }
#pragma unroll
        for (int k = 0; k < 9; k++) {
            float4 v = r2p[k];
            R2[4 * k + 0] = v.x; R2[4 * k + 1] = v.y; R2[4 * k + 2] = v.z; R2[4 * k + 3] = v.w;
        }
#pragma unroll
        for (int g = 0; g < 4; g++) {
            float s0 = fmaxf(S2[3 * g + 0], EPSF);
            float s1 = fmaxf(S2[3 * g + 1], EPSF);
            float s2 = fmaxf(S2[3 * g + 2], EPSF);
            const float* R = R2 + 9 * g;
            float c00 = R[0] * s0 * R[0] + R[1] * s1 * R[1] + R[2] * s2 * R[2];
            float c11 = R[3] * s0 * R[3] + R[4] * s1 * R[4] + R[5] * s2 * R[5];
            float c22 = R[6] * s0 * R[6] + R[7] * s1 * R[7] + R[8] * s2 * R[8];
            float c01 = R[0] * s0 * R[3] + R[1] * s1 * R[4] + R[2] * s2 * R[5];
            float c02 = R[0] * s0 * R[6] + R[1] * s1 * R[7] + R[2] * s2 * R[8];
            float c12 = R[3] * s0 * R[6] + R[4] * s1 * R[7] + R[5] * s2 * R[8];
            cov2[g][0] = c00; cov2[g][1] = c11; cov2[g][2] = c22;
            cov2[g][3] = c01; cov2[g][4] = c02; cov2[g][5] = c12;
            tr_cov2[g] = c00 + c11 + c22;
        }
    }

    // ---- Phase C: rotate into frame 1, scale by sqrt(s1), eigensolve ----
    float res[4];
    {
        float S1[12], R1[36];
#pragma unroll
        for (int k = 0; k < 3; k++) {
            float4 v = s1p[k];
            S1[4 * k + 0] = v.x; S1[4 * k + 1] = v.y; S1[4 * k + 2] = v.z; S1[4 * k + 3] = v.w;
        }
#pragma unroll
        for (int k = 0; k < 9; k++) {
            float4 v = r1p[k];
            R1[4 * k + 0] = v.x; R1[4 * k + 1] = v.y; R1[4 * k + 2] = v.z; R1[4 * k + 3] = v.w;
        }
#pragma unroll
        for (int g = 0; g < 4; g++) {
            float s0 = fmaxf(S1[3 * g + 0], EPSF);
            float s1 = fmaxf(S1[3 * g + 1], EPSF);
            float s2 = fmaxf(S1[3 * g + 2], EPSF);
            const float* R = R1 + 9 * g;
            float C[3][3];
            C[0][0] = cov2[g][0]; C[1][1] = cov2[g][1]; C[2][2] = cov2[g][2];
            C[0][1] = C[1][0] = cov2[g][3];
            C[0][2] = C[2][0] = cov2[g][4];
            C[1][2] = C[2][1] = cov2[g][5];

            float T[3][3];
#pragma unroll
            for (int r = 0; r < 3; r++)
#pragma unroll
                for (int c = 0; c < 3; c++)
                    T[r][c] = C[r][0] * R[c] + C[r][1] * R[3 + c] + C[r][2] * R[6 + c];

            float M[3][3];
#pragma unroll
            for (int r = 0; r < 3; r++)
#pragma unroll
                for (int c = 0; c < 3; c++)
                    M[r][c] = R[r] * T[0][c] + R[3 + r] * T[1][c] + R[6 + r] * T[2][c];

            float ss0 = sqrtf(s0), ss1 = sqrtf(s1), ss2 = sqrtf(s2);
            double a00 = (double)(s0 * M[0][0]) + 1e-8;
            double a11 = (double)(s1 * M[1][1]) + 1e-8;
            double a22 = (double)(s2 * M[2][2]) + 1e-8;
            double a01 = (double)(0.5f * (M[0][1] + M[1][0]) * ss0 * ss1);
            double a02 = (double)(0.5f * (M[0][2] + M[2][0]) * ss0 * ss2);
            double a12 = (double)(0.5f * (M[1][2] + M[2][1]) * ss1 * ss2);

            float trs = tr_sqrt_eig(a00, a11, a22, a01, a02, a12);

            float cov_w = (s0 + s1 + s2) + tr_cov2[g] - 2.0f * trs;
            cov_w = fmaxf(cov_w, 0.0f);
            res[g] = sqrtf(fmaxf(loc_diff2[g] + cov_w, EPSF));
        }
    }

    float4 o;
    o.x = res[0]; o.y = res[1]; o.z = res[2]; o.w = res[3];
    ((float4*)out)[t] = o;
}

extern "C" void kernel_launch(void* const* d_in, const int* in_sizes, int n_in,
                              void* d_out, int out_size, void* d_ws, size_t ws_size,
                              hipStream_t stream) {
    const float* loc1   = (const float*)d_in[0];
    const float* scale1 = (const float*)d_in[1];
    const float* rot1   = (const float*)d_in[2];
    const float* loc2   = (const float*)d_in[3];
    const float* scale2 = (const float*)d_in[4];
    const float* rot2   = (const float*)d_in[5];
    float* out = (float*)d_out;

    int B = in_sizes[0] / 3;   // 1048576, divisible by 4
    int B4 = B / 4;            // 262144 threads
    int block = 64;            // one wave per block -> fine-grained scheduling
    int grid = (B4 + block - 1) / block;   // 4096 blocks
    wasserstein_kernel<<<grid, block, 0, stream>>>(loc1, scale1, rot1, loc2, scale2, rot2, out, B4);
}

// Round 4
// 147.326 us; speedup vs baseline: 1.0895x; 1.0895x over previous
//
#include <hip/hip_runtime.h>
#include <math.h>

#define EPSF 1e-8f

// Sum of sqrt(clip(eigvals,1e-8)) of a symmetric 3x3.
// fp64 only for cancellation-sensitive invariants (q, b, p2, detB, r);
// acos/cos and eigen sqrts in fp32 hardware ops. No fp64 division.
__device__ __forceinline__ float tr_sqrt_eig(double a00, double a11, double a22,
                                             double a01, double a02, double a12)
{
    double q = (a00 + a11 + a22) * (1.0 / 3.0);
    double b00 = a00 - q, b11 = a11 - q, b22 = a22 - q;
    double p1 = a01 * a01 + a02 * a02 + a12 * a12;
    double p2 = b00 * b00 + b11 * b11 + b22 * b22 + 2.0 * p1;

    if (p2 <= 1e-30) {   // triple-degenerate: all eigs = q
        return 3.0f * sqrtf(fmaxf((float)q, EPSF));
    }

    double x = p2 * (1.0 / 6.0);
    double inv = rsqrt(x);          // (p2/6)^{-1/2}
    double p = x * inv;             // sqrt(p2/6)
    double detB = b00 * (b11 * b22 - a12 * a12)
                - a01 * (a01 * b22 - a12 * a02)
                + a02 * (a01 * a12 - b11 * a02);
    double r = 0.5 * detB * (inv * inv * inv);
    r = fmin(1.0, fmax(-1.0, r));

    float phi = acosf((float)r) * (1.0f / 3.0f);
    float qf = (float)q;
    float tp = 2.0f * (float)p;
    float e0 = qf + tp * cosf(phi);
    float e1 = qf + tp * cosf(phi - 2.0943951023931953f);  // -2*pi/3
    float e2 = qf + tp * cosf(phi + 2.0943951023931953f);  // +2*pi/3
    return sqrtf(fmaxf(e0, EPSF)) + sqrtf(fmaxf(e1, EPSF)) + sqrtf(fmaxf(e2, EPSF));
}

// 1 Gaussian per thread (16384 waves -> full TLP).
// rot1/rot2 (36 B/gaussian, 75% of traffic) staged block-cooperatively into
// LDS with coalesced float4 loads; loc/scale loaded directly (12 B stride).
// LDS read stride 9 floats is coprime with 32 banks -> conflict-free.
__global__ __launch_bounds__(256) void wasserstein_kernel(
    const float* __restrict__ loc1, const float* __restrict__ scale1,
    const float* __restrict__ rot1, const float* __restrict__ loc2,
    const float* __restrict__ scale2, const float* __restrict__ rot2,
    float* __restrict__ out, int B)
{
    __shared__ float sR1[256 * 9];
    __shared__ float sR2[256 * 9];

    const int tid = threadIdx.x;
    const int g = blockIdx.x * 256 + tid;

    // ---- cooperative staging: 256 rot matrices = 576 float4 per array ----
    {
        const float4* r1g = (const float4*)rot1 + blockIdx.x * 576;
        const float4* r2g = (const float4*)rot2 + blockIdx.x * 576;
        float4* s1 = (float4*)sR1;
        float4* s2 = (float4*)sR2;
        s1[tid]       = r1g[tid];
        s1[tid + 256] = r1g[tid + 256];
        s2[tid]       = r2g[tid];
        s2[tid + 256] = r2g[tid + 256];
        if (tid < 64) {
            s1[tid + 512] = r1g[tid + 512];
            s2[tid + 512] = r2g[tid + 512];
        }
    }

    // ---- direct loads (independent, issued before the barrier wait) ----
    float a0 = loc1[3 * g], a1 = loc1[3 * g + 1], a2 = loc1[3 * g + 2];
    float b0 = loc2[3 * g], b1 = loc2[3 * g + 1], b2 = loc2[3 * g + 2];
    float s10 = fmaxf(scale1[3 * g], EPSF);
    float s11 = fmaxf(scale1[3 * g + 1], EPSF);
    float s12 = fmaxf(scale1[3 * g + 2], EPSF);
    float s20 = fmaxf(scale2[3 * g], EPSF);
    float s21 = fmaxf(scale2[3 * g + 1], EPSF);
    float s22 = fmaxf(scale2[3 * g + 2], EPSF);

    float d0 = a0 - b0, d1 = a1 - b1, d2 = a2 - b2;
    float loc_diff2 = d0 * d0 + d1 * d1 + d2 * d2;

    __syncthreads();

    const float* R2 = sR2 + 9 * tid;
    float R2r[9];
#pragma unroll
    for (int k = 0; k < 9; k++) R2r[k] = R2[k];

    // cov2[r][c] = sum_j R2[r][j]*s2[j]*R2[c][j]  (symmetric)
    float C[3][3];
    C[0][0] = R2r[0] * s20 * R2r[0] + R2r[1] * s21 * R2r[1] + R2r[2] * s22 * R2r[2];
    C[1][1] = R2r[3] * s20 * R2r[3] + R2r[4] * s21 * R2r[4] + R2r[5] * s22 * R2r[5];
    C[2][2] = R2r[6] * s20 * R2r[6] + R2r[7] * s21 * R2r[7] + R2r[8] * s22 * R2r[8];
    C[0][1] = C[1][0] = R2r[0] * s20 * R2r[3] + R2r[1] * s21 * R2r[4] + R2r[2] * s22 * R2r[5];
    C[0][2] = C[2][0] = R2r[0] * s20 * R2r[6] + R2r[1] * s21 * R2r[7] + R2r[2] * s22 * R2r[8];
    C[1][2] = C[2][1] = R2r[3] * s20 * R2r[6] + R2r[4] * s21 * R2r[7] + R2r[5] * s22 * R2r[8];
    float tr_cov2 = C[0][0] + C[1][1] + C[2][2];

    const float* R1 = sR1 + 9 * tid;
    float R1r[9];
#pragma unroll
    for (int k = 0; k < 9; k++) R1r[k] = R1[k];

    // T = C * R1
    float T[3][3];
#pragma unroll
    for (int r = 0; r < 3; r++)
#pragma unroll
        for (int c = 0; c < 3; c++)
            T[r][c] = C[r][0] * R1r[c] + C[r][1] * R1r[3 + c] + C[r][2] * R1r[6 + c];

    // M = R1^T * T
    float M[3][3];
#pragma unroll
    for (int r = 0; r < 3; r++)
#pragma unroll
        for (int c = 0; c < 3; c++)
            M[r][c] = R1r[r] * T[0][c] + R1r[3 + r] * T[1][c] + R1r[6 + r] * T[2][c];

    float ss0 = sqrtf(s10), ss1 = sqrtf(s11), ss2 = sqrtf(s12);
    double a00 = (double)(s10 * M[0][0]) + 1e-8;
    double a11 = (double)(s11 * M[1][1]) + 1e-8;
    double a22 = (double)(s12 * M[2][2]) + 1e-8;
    double a01 = (double)(0.5f * (M[0][1] + M[1][0]) * ss0 * ss1);
    double a02 = (double)(0.5f * (M[0][2] + M[2][0]) * ss0 * ss2);
    double a12 = (double)(0.5f * (M[1][2] + M[2][1]) * ss1 * ss2);

    float trs = tr_sqrt_eig(a00, a11, a22, a01, a02, a12);

    float cov_w = (s10 + s11 + s12) + tr_cov2 - 2.0f * trs;
    cov_w = fmaxf(cov_w, 0.0f);
    out[g] = sqrtf(fmaxf(loc_diff2 + cov_w, EPSF));
}

extern "C" void kernel_launch(void* const* d_in, const int* in_sizes, int n_in,
                              void* d_out, int out_size, void* d_ws, size_t ws_size,
                              hipStream_t stream) {
    const float* loc1   = (const float*)d_in[0];
    const float* scale1 = (const float*)d_in[1];
    const float* rot1   = (const float*)d_in[2];
    const float* loc2   = (const float*)d_in[3];
    const float* scale2 = (const float*)d_in[4];
    const float* rot2   = (const float*)d_in[5];
    float* out = (float*)d_out;

    int B = in_sizes[0] / 3;        // 1048576, divisible by 256
    int grid = B / 256;             // 4096 blocks x 4 waves = 16384 waves
    wasserstein_kernel<<<grid, 256, 0, stream>>>(loc1, scale1, rot1, loc2, scale2, rot2, out, B);
}

// Round 5
// 147.270 us; speedup vs baseline: 1.0899x; 1.0004x over previous
//
#include <hip/hip_runtime.h>
#include <math.h>

#define EPSF 1e-8f

// Sum of sqrt(clip(eigvals,1e-8)) of a symmetric 3x3.
// fp64 only for cancellation-sensitive invariants (q, b, p2, detB, r);
// transcendentals and eigen sqrts in fp32. Branchless (p2 floored at 1e-60:
// then |b|,|a| <= 1e-30, detB ~ p2^1.5 -> r finite, p ~ 1e-30 -> e == q).
__device__ __forceinline__ float tr_sqrt_eig(double a00, double a11, double a22,
                                             double a01, double a02, double a12)
{
    double q = (a00 + a11 + a22) * (1.0 / 3.0);
    double b00 = a00 - q, b11 = a11 - q, b22 = a22 - q;
    double p1 = a01 * a01 + a02 * a02 + a12 * a12;
    double p2 = b00 * b00 + b11 * b11 + b22 * b22 + 2.0 * p1;
    p2 = fmax(p2, 1e-60);

    double x = p2 * (1.0 / 6.0);
    double inv = rsqrt(x);          // (p2/6)^{-1/2}
    double p = x * inv;             // sqrt(p2/6)
    double detB = b00 * (b11 * b22 - a12 * a12)
                - a01 * (a01 * b22 - a12 * a02)
                + a02 * (a01 * a12 - b11 * a02);
    double r = 0.5 * detB * (inv * inv * inv);
    r = fmin(1.0, fmax(-1.0, r));

    // phi in [0, pi/3]; cos(phi +- 2pi/3) = -0.5 c -+ (sqrt(3)/2) s
    float phi = acosf((float)r) * (1.0f / 3.0f);
    float c, s;
    __sincosf(phi, &s, &c);
    float qf = (float)q;
    float tp = 2.0f * (float)p;
    float e0 = qf + tp * c;
    float e1 = qf + tp * (-0.5f * c - 0.8660254037844386f * s);
    float e2 = qf + tp * (-0.5f * c + 0.8660254037844386f * s);
    return sqrtf(fmaxf(e0, EPSF)) + sqrtf(fmaxf(e1, EPSF)) + sqrtf(fmaxf(e2, EPSF));
}

// 1 Gaussian/thread, 4096 blocks x 256. ALL global reads are block-cooperative
// aligned float4 streaming loads into LDS (1920 chunks/block, ~7.5/thread) --
// the global-access signature of a pure float4 copy kernel. Per-thread LDS
// reads: strides 3 and 9 are coprime with 32 banks -> free 2-way aliasing.
__global__ __launch_bounds__(256) void wasserstein_kernel(
    const float* __restrict__ loc1, const float* __restrict__ scale1,
    const float* __restrict__ rot1, const float* __restrict__ loc2,
    const float* __restrict__ scale2, const float* __restrict__ rot2,
    float* __restrict__ out, int B)
{
    __shared__ float sL1[768], sL2[768], sS1[768], sS2[768];
    __shared__ float sR1[2304], sR2[2304];

    const int tid = threadIdx.x;
    const int g = blockIdx.x * 256 + tid;

    {
        const float4* l1g = (const float4*)loc1   + blockIdx.x * 192;
        const float4* l2g = (const float4*)loc2   + blockIdx.x * 192;
        const float4* s1g = (const float4*)scale1 + blockIdx.x * 192;
        const float4* s2g = (const float4*)scale2 + blockIdx.x * 192;
        const float4* r1g = (const float4*)rot1   + blockIdx.x * 576;
        const float4* r2g = (const float4*)rot2   + blockIdx.x * 576;
        float4* dL1 = (float4*)sL1; float4* dL2 = (float4*)sL2;
        float4* dS1 = (float4*)sS1; float4* dS2 = (float4*)sS2;
        float4* dR1 = (float4*)sR1; float4* dR2 = (float4*)sR2;

        if (tid < 192) {               // 4 chunks: loc/scale
            dL1[tid] = l1g[tid];
            dL2[tid] = l2g[tid];
            dS1[tid] = s1g[tid];
            dS2[tid] = s2g[tid];
        }
        dR1[tid]       = r1g[tid];     // 2 chunks each thread
        dR1[tid + 256] = r1g[tid + 256];
        dR2[tid]       = r2g[tid];
        dR2[tid + 256] = r2g[tid + 256];
        if (tid >= 192) {              // rot tails on the otherwise-idle wave
            dR1[tid + 320] = r1g[tid + 320];   // chunks 512..575
            dR2[tid + 320] = r2g[tid + 320];
        }
    }

    __syncthreads();

    float a0 = sL1[3 * tid], a1 = sL1[3 * tid + 1], a2 = sL1[3 * tid + 2];
    float b0 = sL2[3 * tid], b1 = sL2[3 * tid + 1], b2 = sL2[3 * tid + 2];
    float d0 = a0 - b0, d1 = a1 - b1, d2 = a2 - b2;
    float loc_diff2 = d0 * d0 + d1 * d1 + d2 * d2;

    float s10 = fmaxf(sS1[3 * tid], EPSF);
    float s11 = fmaxf(sS1[3 * tid + 1], EPSF);
    float s12 = fmaxf(sS1[3 * tid + 2], EPSF);
    float s20 = fmaxf(sS2[3 * tid], EPSF);
    float s21 = fmaxf(sS2[3 * tid + 1], EPSF);
    float s22 = fmaxf(sS2[3 * tid + 2], EPSF);

    float R2r[9], R1r[9];
#pragma unroll
    for (int k = 0; k < 9; k++) R2r[k] = sR2[9 * tid + k];
#pragma unroll
    for (int k = 0; k < 9; k++) R1r[k] = sR1[9 * tid + k];

    // cov2[r][c] = sum_j R2[r][j]*s2[j]*R2[c][j]  (symmetric)
    float C[3][3];
    C[0][0] = R2r[0] * s20 * R2r[0] + R2r[1] * s21 * R2r[1] + R2r[2] * s22 * R2r[2];
    C[1][1] = R2r[3] * s20 * R2r[3] + R2r[4] * s21 * R2r[4] + R2r[5] * s22 * R2r[5];
    C[2][2] = R2r[6] * s20 * R2r[6] + R2r[7] * s21 * R2r[7] + R2r[8] * s22 * R2r[8];
    C[0][1] = C[1][0] = R2r[0] * s20 * R2r[3] + R2r[1] * s21 * R2r[4] + R2r[2] * s22 * R2r[5];
    C[0][2] = C[2][0] = R2r[0] * s20 * R2r[6] + R2r[1] * s21 * R2r[7] + R2r[2] * s22 * R2r[8];
    C[1][2] = C[2][1] = R2r[3] * s20 * R2r[6] + R2r[4] * s21 * R2r[7] + R2r[5] * s22 * R2r[8];
    float tr_cov2 = C[0][0] + C[1][1] + C[2][2];

    // T = C * R1 ; M = R1^T * T
    float T[3][3];
#pragma unroll
    for (int r = 0; r < 3; r++)
#pragma unroll
        for (int c = 0; c < 3; c++)
            T[r][c] = C[r][0] * R1r[c] + C[r][1] * R1r[3 + c] + C[r][2] * R1r[6 + c];
    float M[3][3];
#pragma unroll
    for (int r = 0; r < 3; r++)
#pragma unroll
        for (int c = 0; c < 3; c++)
            M[r][c] = R1r[r] * T[0][c] + R1r[3 + r] * T[1][c] + R1r[6 + r] * T[2][c];

    float ss0 = sqrtf(s10), ss1 = sqrtf(s11), ss2 = sqrtf(s12);
    double a00 = (double)(s10 * M[0][0]) + 1e-8;
    double a11 = (double)(s11 * M[1][1]) + 1e-8;
    double a22 = (double)(s12 * M[2][2]) + 1e-8;
    double a01 = (double)(0.5f * (M[0][1] + M[1][0]) * ss0 * ss1);
    double a02 = (double)(0.5f * (M[0][2] + M[2][0]) * ss0 * ss2);
    double a12 = (double)(0.5f * (M[1][2] + M[2][1]) * ss1 * ss2);

    float trs = tr_sqrt_eig(a00, a11, a22, a01, a02, a12);

    float cov_w = (s10 + s11 + s12) + tr_cov2 - 2.0f * trs;
    cov_w = fmaxf(cov_w, 0.0f);
    out[g] = sqrtf(fmaxf(loc_diff2 + cov_w, EPSF));
}

extern "C" void kernel_launch(void* const* d_in, const int* in_sizes, int n_in,
                              void* d_out, int out_size, void* d_ws, size_t ws_size,
                              hipStream_t stream) {
    const float* loc1   = (const float*)d_in[0];
    const float* scale1 = (const float*)d_in[1];
    const float* rot1   = (const float*)d_in[2];
    const float* loc2   = (const float*)d_in[3];
    const float* scale2 = (const float*)d_in[4];
    const float* rot2   = (const float*)d_in[5];
    float* out = (float*)d_out;

    int B = in_sizes[0] / 3;        // 1048576, divisible by 256
    int grid = B / 256;             // 4096 blocks
    wasserstein_kernel<<<grid, 256, 0, stream>>>(loc1, scale1, rot1, loc2, scale2, rot2, out, B);
}

// Round 7
// 140.799 us; speedup vs baseline: 1.1400x; 1.0460x over previous
//
#include <hip/hip_runtime.h>
#include <math.h>

#define EPSF 1e-8f

typedef float nfloat4 __attribute__((ext_vector_type(4)));

// Sum of sqrt(clip(eigvals,1e-8)) of a symmetric 3x3.
// fp64 only for cancellation-sensitive invariants (q, b, p2, detB, r);
// transcendentals and eigen sqrts in fp32. Branchless (p2 floored at 1e-60).
__device__ __forceinline__ float tr_sqrt_eig(double a00, double a11, double a22,
                                             double a01, double a02, double a12)
{
    double q = (a00 + a11 + a22) * (1.0 / 3.0);
    double b00 = a00 - q, b11 = a11 - q, b22 = a22 - q;
    double p1 = a01 * a01 + a02 * a02 + a12 * a12;
    double p2 = b00 * b00 + b11 * b11 + b22 * b22 + 2.0 * p1;
    p2 = fmax(p2, 1e-60);

    double x = p2 * (1.0 / 6.0);
    double inv = rsqrt(x);          // (p2/6)^{-1/2}
    double p = x * inv;             // sqrt(p2/6)
    double detB = b00 * (b11 * b22 - a12 * a12)
                - a01 * (a01 * b22 - a12 * a02)
                + a02 * (a01 * a12 - b11 * a02);
    double r = 0.5 * detB * (inv * inv * inv);
    r = fmin(1.0, fmax(-1.0, r));

    // phi in [0, pi/3]; cos(phi +- 2pi/3) = -0.5 c -+ (sqrt(3)/2) s
    float phi = acosf((float)r) * (1.0f / 3.0f);
    float c, s;
    __sincosf(phi, &s, &c);
    float qf = (float)q;
    float tp = 2.0f * (float)p;
    float e0 = qf + tp * c;
    float e1 = qf + tp * (-0.5f * c - 0.8660254037844386f * s);
    float e2 = qf + tp * (-0.5f * c + 0.8660254037844386f * s);
    return sqrtf(fmaxf(e0, EPSF)) + sqrtf(fmaxf(e1, EPSF)) + sqrtf(fmaxf(e2, EPSF));
}

// Round-5 structure, but ALL global reads are NON-TEMPORAL 16B loads
// (no L2/L3 allocation -> no dirty-line evictions of the harness's 268 MB
// poison fill competing for HBM). Data is single-touch; caching it was pure
// cost under the eviction theory.
__global__ __launch_bounds__(256) void wasserstein_kernel(
    const float* __restrict__ loc1, const float* __restrict__ scale1,
    const float* __restrict__ rot1, const float* __restrict__ loc2,
    const float* __restrict__ scale2, const float* __restrict__ rot2,
    float* __restrict__ out, int B)
{
    __shared__ float sL1[768], sL2[768], sS1[768], sS2[768];
    __shared__ float sR1[2304], sR2[2304];

    const int tid = threadIdx.x;
    const int g = blockIdx.x * 256 + tid;

    {
        const nfloat4* l1g = (const nfloat4*)loc1   + blockIdx.x * 192;
        const nfloat4* l2g = (const nfloat4*)loc2   + blockIdx.x * 192;
        const nfloat4* s1g = (const nfloat4*)scale1 + blockIdx.x * 192;
        const nfloat4* s2g = (const nfloat4*)scale2 + blockIdx.x * 192;
        const nfloat4* r1g = (const nfloat4*)rot1   + blockIdx.x * 576;
        const nfloat4* r2g = (const nfloat4*)rot2   + blockIdx.x * 576;
        nfloat4* dL1 = (nfloat4*)sL1; nfloat4* dL2 = (nfloat4*)sL2;
        nfloat4* dS1 = (nfloat4*)sS1; nfloat4* dS2 = (nfloat4*)sS2;
        nfloat4* dR1 = (nfloat4*)sR1; nfloat4* dR2 = (nfloat4*)sR2;

        if (tid < 192) {               // loc/scale chunks
            dL1[tid] = __builtin_nontemporal_load(&l1g[tid]);
            dL2[tid] = __builtin_nontemporal_load(&l2g[tid]);
            dS1[tid] = __builtin_nontemporal_load(&s1g[tid]);
            dS2[tid] = __builtin_nontemporal_load(&s2g[tid]);
        }
        dR1[tid]       = __builtin_nontemporal_load(&r1g[tid]);
        dR1[tid + 256] = __builtin_nontemporal_load(&r1g[tid + 256]);
        dR2[tid]       = __builtin_nontemporal_load(&r2g[tid]);
        dR2[tid + 256] = __builtin_nontemporal_load(&r2g[tid + 256]);
        if (tid >= 192) {              // rot tails (chunks 512..575)
            dR1[tid + 320] = __builtin_nontemporal_load(&r1g[tid + 320]);
            dR2[tid + 320] = __builtin_nontemporal_load(&r2g[tid + 320]);
        }
    }

    __syncthreads();

    float a0 = sL1[3 * tid], a1 = sL1[3 * tid + 1], a2 = sL1[3 * tid + 2];
    float b0 = sL2[3 * tid], b1 = sL2[3 * tid + 1], b2 = sL2[3 * tid + 2];
    float d0 = a0 - b0, d1 = a1 - b1, d2 = a2 - b2;
    float loc_diff2 = d0 * d0 + d1 * d1 + d2 * d2;

    float s10 = fmaxf(sS1[3 * tid], EPSF);
    float s11 = fmaxf(sS1[3 * tid + 1], EPSF);
    float s12 = fmaxf(sS1[3 * tid + 2], EPSF);
    float s20 = fmaxf(sS2[3 * tid], EPSF);
    float s21 = fmaxf(sS2[3 * tid + 1], EPSF);
    float s22 = fmaxf(sS2[3 * tid + 2], EPSF);

    float R2r[9], R1r[9];
#pragma unroll
    for (int k = 0; k < 9; k++) R2r[k] = sR2[9 * tid + k];
#pragma unroll
    for (int k = 0; k < 9; k++) R1r[k] = sR1[9 * tid + k];

    // cov2[r][c] = sum_j R2[r][j]*s2[j]*R2[c][j]  (symmetric)
    float C[3][3];
    C[0][0] = R2r[0] * s20 * R2r[0] + R2r[1] * s21 * R2r[1] + R2r[2] * s22 * R2r[2];
    C[1][1] = R2r[3] * s20 * R2r[3] + R2r[4] * s21 * R2r[4] + R2r[5] * s22 * R2r[5];
    C[2][2] = R2r[6] * s20 * R2r[6] + R2r[7] * s21 * R2r[7] + R2r[8] * s22 * R2r[8];
    C[0][1] = C[1][0] = R2r[0] * s20 * R2r[3] + R2r[1] * s21 * R2r[4] + R2r[2] * s22 * R2r[5];
    C[0][2] = C[2][0] = R2r[0] * s20 * R2r[6] + R2r[1] * s21 * R2r[7] + R2r[2] * s22 * R2r[8];
    C[1][2] = C[2][1] = R2r[3] * s20 * R2r[6] + R2r[4] * s21 * R2r[7] + R2r[5] * s22 * R2r[8];
    float tr_cov2 = C[0][0] + C[1][1] + C[2][2];

    // T = C * R1 ; M = R1^T * T
    float T[3][3];
#pragma unroll
    for (int r = 0; r < 3; r++)
#pragma unroll
        for (int c = 0; c < 3; c++)
            T[r][c] = C[r][0] * R1r[c] + C[r][1] * R1r[3 + c] + C[r][2] * R1r[6 + c];
    float M[3][3];
#pragma unroll
    for (int r = 0; r < 3; r++)
#pragma unroll
        for (int c = 0; c < 3; c++)
            M[r][c] = R1r[r] * T[0][c] + R1r[3 + r] * T[1][c] + R1r[6 + r] * T[2][c];

    float ss0 = sqrtf(s10), ss1 = sqrtf(s11), ss2 = sqrtf(s12);
    double a00 = (double)(s10 * M[0][0]) + 1e-8;
    double a11 = (double)(s11 * M[1][1]) + 1e-8;
    double a22 = (double)(s12 * M[2][2]) + 1e-8;
    double a01 = (double)(0.5f * (M[0][1] + M[1][0]) * ss0 * ss1);
    double a02 = (double)(0.5f * (M[0][2] + M[2][0]) * ss0 * ss2);
    double a12 = (double)(0.5f * (M[1][2] + M[2][1]) * ss1 * ss2);

    float trs = tr_sqrt_eig(a00, a11, a22, a01, a02, a12);

    float cov_w = (s10 + s11 + s12) + tr_cov2 - 2.0f * trs;
    cov_w = fmaxf(cov_w, 0.0f);
    float result = sqrtf(fmaxf(loc_diff2 + cov_w, EPSF));
    __builtin_nontemporal_store(result, &out[g]);
}

extern "C" void kernel_launch(void* const* d_in, const int* in_sizes, int n_in,
                              void* d_out, int out_size, void* d_ws, size_t ws_size,
                              hipStream_t stream) {
    const float* loc1   = (const float*)d_in[0];
    const float* scale1 = (const float*)d_in[1];
    const float* rot1   = (const float*)d_in[2];
    const float* loc2   = (const float*)d_in[3];
    const float* scale2 = (const float*)d_in[4];
    const float* rot2   = (const float*)d_in[5];
    float* out = (float*)d_out;

    int B = in_sizes[0] / 3;        // 1048576, divisible by 256
    int grid = B / 256;             // 4096 blocks
    wasserstein_kernel<<<grid, 256, 0, stream>>>(loc1, scale1, rot1, loc2, scale2, rot2, out, B);
}